// Round 19
// baseline (236.829 us; speedup 1.0000x reference)
//
#include <hip/hip_runtime.h>
#include <hip/hip_cooperative_groups.h>

namespace cg = cooperative_groups;

// GraphConv: ONE cooperative sort kernel + fused bf16 gather + per-block MFMA GEMM.
// Round 19: collapse p1_histo_conv/p1_scanrow/p1_scatter/p2_all into k_sort_coop
//   (grid=256 blocks, grid.sync() between phases; conversion uses 8-way-unrolled
//   independent loads to saturate BW at 256 blocks). 5 -> 2 dispatches.
//   Fused gather+GEMM kernel unchanged from round 18 (proven 80.5us).

constexpr int N_NODES = 100000;
constexpr int D = 128;
constexpr int NB = 256;                        // coarse buckets == chunks == coop grid
constexpr int GROUP = (N_NODES + NB - 1) / NB; // 391 nodes per bucket
constexpr int CAP = 14336;                     // LDS esrc staging capacity (56KB)
constexpr int CONVB = 1280;                    // conversion blocks (fallback path)
constexpr int RPAD = 136;                      // LDS A-tile row stride in ushorts (272B)

typedef float f32x4 __attribute__((ext_vector_type(4)));
typedef short short8 __attribute__((ext_vector_type(8)));
typedef unsigned uint4v __attribute__((ext_vector_type(4)));

__device__ __forceinline__ ushort f2bf(float x) {            // fp32 -> bf16 RNE
    unsigned u = __float_as_uint(x);
    return (ushort)((u + 0x7fffu + ((u >> 16) & 1u)) >> 16);
}
__device__ __forceinline__ float bf2f(ushort h) {
    return __uint_as_float(((unsigned)h) << 16);
}
__device__ __forceinline__ uint2 conv4(const f32x4 v) {
    uint2 o;
    o.x = (unsigned)f2bf(v[0]) | ((unsigned)f2bf(v[1]) << 16);
    o.y = (unsigned)f2bf(v[2]) | ((unsigned)f2bf(v[3]) << 16);
    return o;
}

// ================= cooperative sort: all 4 phases in one dispatch =================
__global__ __launch_bounds__(256) void k_sort_coop(const int* __restrict__ src,
                                                   const int* __restrict__ dst, int E,
                                                   const float* __restrict__ W,
                                                   ushort* __restrict__ whi,
                                                   ushort* __restrict__ wlo,
                                                   const float* __restrict__ feat,
                                                   uint2* __restrict__ ft2,
                                                   int* __restrict__ bhist,   // [bucket][chunk]
                                                   int* __restrict__ rowtot,
                                                   int* __restrict__ pairs,
                                                   int* __restrict__ deg,
                                                   int* __restrict__ offs,
                                                   float* __restrict__ norm,
                                                   int* __restrict__ esrc) {
    cg::grid_group grid = cg::this_grid();
    __shared__ int sh_h[512];
    __shared__ int sh_a[256];
    __shared__ int sh_b[256];
    __shared__ int sbuf[CAP];
    const int t = threadIdx.x, b = blockIdx.x;

    // ---- phase 0: W pack (blocks 0..63) ----
    if (b < 64) {
        int p = b * 256 + t;
        int i  = p & 7;
        int l  = (p >> 3) & 63;
        int kt = (p >> 9) & 3;
        int ct = (p >> 11);
        int k = kt * 32 + (l >> 4) * 8 + i;
        int n = ct * 16 + (l & 15);
        float x = W[k * 128 + n];
        ushort hh = f2bf(x);
        whi[p] = hh;
        wlo[p] = f2bf(x - bf2f(hh));
    }

    // ---- phase 1: feat -> bf16 (8-way unrolled independent loads for MLP) ----
    {
        const int total = N_NODES * 32;          // uint2 elements
        const int stride = NB * 256;
        int i = b * 256 + t;
        const f32x4* fv = (const f32x4*)feat;
        for (; i + 7 * stride < total; i += 8 * stride) {
            f32x4 v0 = fv[i];
            f32x4 v1 = fv[i + stride];
            f32x4 v2 = fv[i + 2 * stride];
            f32x4 v3 = fv[i + 3 * stride];
            f32x4 v4 = fv[i + 4 * stride];
            f32x4 v5 = fv[i + 5 * stride];
            f32x4 v6 = fv[i + 6 * stride];
            f32x4 v7 = fv[i + 7 * stride];
            ft2[i]              = conv4(v0);
            ft2[i + stride]     = conv4(v1);
            ft2[i + 2 * stride] = conv4(v2);
            ft2[i + 3 * stride] = conv4(v3);
            ft2[i + 4 * stride] = conv4(v4);
            ft2[i + 5 * stride] = conv4(v5);
            ft2[i + 6 * stride] = conv4(v6);
            ft2[i + 7 * stride] = conv4(v7);
        }
        for (; i < total; i += stride) ft2[i] = conv4(((const f32x4*)feat)[i]);
    }

    // ---- phase 2: coarse histogram of chunk b ----
    sh_h[t] = 0;
    __syncthreads();
    const int per = (E + NB - 1) / NB;
    {
        int s = b * per, e = min(E, s + per);
        for (int i = s + t; i < e; i += 256) atomicAdd(&sh_h[dst[i] / GROUP], 1);
    }
    __syncthreads();
    bhist[t * NB + b] = sh_h[t];                 // bucket-major [bucket][chunk]
    grid.sync();

    // ---- phase 3: block b exclusive-scans bucket row b over chunks ----
    {
        int v = bhist[b * NB + t];
        sh_a[t] = v; __syncthreads();
        for (int off = 1; off < 256; off <<= 1) {
            int x = (t >= off) ? sh_a[t - off] : 0;
            __syncthreads();
            sh_a[t] += x;
            __syncthreads();
        }
        bhist[b * NB + t] = sh_a[t] - v;
        if (t == 255) rowtot[b] = sh_a[255];
    }
    grid.sync();

    // ---- phase 4: scatter chunk b into coarse-bucket regions ----
    {
        int rv = rowtot[t];
        sh_a[t] = rv; __syncthreads();
        for (int off = 1; off < 256; off <<= 1) {
            int x = (t >= off) ? sh_a[t - off] : 0;
            __syncthreads();
            sh_a[t] += x;
            __syncthreads();
        }
        sh_b[t] = bhist[t * NB + b] + sh_a[t] - rv;   // chunk offset + bucket base
        __syncthreads();
        int s = b * per, e = min(E, s + per);
        for (int i = s + t; i < e; i += 256) {
            int d = dst[i];
            int bk = d / GROUP;
            int pos = atomicAdd(&sh_b[bk], 1);
            pairs[pos] = ((d - bk * GROUP) << 17) | src[i];
        }
    }
    grid.sync();

    // ---- phase 5: bucket b -> deg/offs/norm + esrc scatter ----
    {
        int lo = b * GROUP;
        int cnt = min(GROUP, N_NODES - lo);
        int rv = rowtot[t];
        sh_a[t] = rv;
        sh_h[t] = 0; sh_h[t + 256] = 0;
        __syncthreads();
        for (int off = 1; off < 256; off <<= 1) {
            int x = (t >= off) ? sh_a[t - off] : 0;
            __syncthreads();
            sh_a[t] += x;
            __syncthreads();
        }
        int s1 = sh_a[b];
        int s0 = s1 - rowtot[b];
        __syncthreads();

        for (int i = s0 + t; i < s1; i += 256) atomicAdd(&sh_h[pairs[i] >> 17], 1);
        __syncthreads();

        int v0 = sh_h[2 * t], v1 = sh_h[2 * t + 1];
        int s = v0 + v1;
        sh_b[t] = s; __syncthreads();
        for (int off = 1; off < 256; off <<= 1) {
            int x = (t >= off) ? sh_b[t - off] : 0;
            __syncthreads();
            sh_b[t] += x;
            __syncthreads();
        }
        int pre = sh_b[t] - s;
        if (2 * t < cnt) {
            int node = lo + 2 * t;
            deg[node] = v0;
            offs[node] = s0 + pre;
            norm[node] = rsqrtf(fmaxf((float)v0, 1.0f));
        }
        if (2 * t + 1 < cnt) {
            int node = lo + 2 * t + 1;
            deg[node] = v1;
            offs[node] = s0 + pre + v0;
            norm[node] = rsqrtf(fmaxf((float)v1, 1.0f));
        }
        __syncthreads();
        sh_h[2 * t] = pre;
        sh_h[2 * t + 1] = pre + v0;
        __syncthreads();

        int wsize = s1 - s0;
        bool fits = (wsize <= CAP);
        for (int i = s0 + t; i < s1; i += 256) {
            int p = pairs[i];
            int dl = p >> 17;
            int sv = p & 0x1FFFF;
            int pos = atomicAdd(&sh_h[dl], 1);
            if (fits) sbuf[pos] = sv; else esrc[s0 + pos] = sv;
        }
        __syncthreads();
        if (fits)
            for (int i = t; i < wsize; i += 256) esrc[s0 + i] = sbuf[i];
    }
}

// ================= fallback separate sort kernels (round 18, proven) =================
__global__ __launch_bounds__(256) void p1_histo_conv(const int* __restrict__ dst, int E,
                                                     int* __restrict__ bhist,
                                                     const float* __restrict__ W,
                                                     ushort* __restrict__ whi,
                                                     ushort* __restrict__ wlo,
                                                     const float* __restrict__ feat,
                                                     uint2* __restrict__ ft2) {
    int t = threadIdx.x, blk = blockIdx.x;
    if (blk >= NB) {
        int base = (blk - NB) * 256 + t;
        int stride = CONVB * 256;
        for (int i = base; i < N_NODES * 32; i += stride)
            ft2[i] = conv4(((const f32x4*)feat)[i]);
        return;
    }
    __shared__ int h[NB];
    h[t] = 0;
    if (blk < 64) {
        int p = blk * 256 + t;
        int i  = p & 7;
        int l  = (p >> 3) & 63;
        int kt = (p >> 9) & 3;
        int ct = (p >> 11);
        int k = kt * 32 + (l >> 4) * 8 + i;
        int n = ct * 16 + (l & 15);
        float x = W[k * 128 + n];
        ushort hh = f2bf(x);
        whi[p] = hh;
        wlo[p] = f2bf(x - bf2f(hh));
    }
    __syncthreads();
    int per = (E + NB - 1) / NB;
    int s = blk * per, e = min(E, s + per);
    for (int i = s + t; i < e; i += 256) atomicAdd(&h[dst[i] / GROUP], 1);
    __syncthreads();
    bhist[t * NB + blk] = h[t];
}

__global__ __launch_bounds__(256) void p1_scanrow(int* __restrict__ bhist,
                                                  int* __restrict__ rowtot) {
    __shared__ int lds[256];
    int b = blockIdx.x, t = threadIdx.x;
    int v = bhist[b * NB + t];
    lds[t] = v; __syncthreads();
    for (int off = 1; off < 256; off <<= 1) {
        int x = (t >= off) ? lds[t - off] : 0;
        __syncthreads();
        lds[t] += x;
        __syncthreads();
    }
    bhist[b * NB + t] = lds[t] - v;
    if (t == 255) rowtot[b] = lds[255];
}

__global__ __launch_bounds__(256) void p1_scatter(const int* __restrict__ src,
                                                  const int* __restrict__ dst, int E,
                                                  const int* __restrict__ bhist,
                                                  const int* __restrict__ rowtot,
                                                  int* __restrict__ pairs) {
    __shared__ int loff[NB];
    __shared__ int bb[NB];
    int t = threadIdx.x, blk = blockIdx.x;
    int rv = rowtot[t];
    bb[t] = rv; __syncthreads();
    for (int off = 1; off < 256; off <<= 1) {
        int x = (t >= off) ? bb[t - off] : 0;
        __syncthreads();
        bb[t] += x;
        __syncthreads();
    }
    loff[t] = bhist[t * NB + blk] + bb[t] - rv;
    __syncthreads();
    int per = (E + NB - 1) / NB;
    int s = blk * per, e = min(E, s + per);
    for (int i = s + t; i < e; i += 256) {
        int d = dst[i];
        int b = d / GROUP;
        int pos = atomicAdd(&loff[b], 1);
        pairs[pos] = ((d - b * GROUP) << 17) | src[i];
    }
}

__global__ __launch_bounds__(256) void p2_all(const int* __restrict__ pairs,
                                              const int* __restrict__ rowtot,
                                              int* __restrict__ deg,
                                              int* __restrict__ offs,
                                              float* __restrict__ norm,
                                              int* __restrict__ esrc) {
    __shared__ int h[512];
    __shared__ int ssum[256];
    __shared__ int bb[256];
    __shared__ int sbuf[CAP];
    int t = threadIdx.x, b = blockIdx.x;
    int lo = b * GROUP;
    int cnt = min(GROUP, N_NODES - lo);

    int rv = rowtot[t];
    bb[t] = rv;
    h[t] = 0; h[t + 256] = 0;
    __syncthreads();
    for (int off = 1; off < 256; off <<= 1) {
        int x = (t >= off) ? bb[t - off] : 0;
        __syncthreads();
        bb[t] += x;
        __syncthreads();
    }
    int s1 = bb[b];
    int s0 = s1 - rowtot[b];
    __syncthreads();

    for (int i = s0 + t; i < s1; i += 256) atomicAdd(&h[pairs[i] >> 17], 1);
    __syncthreads();

    int v0 = h[2 * t], v1 = h[2 * t + 1];
    int s = v0 + v1;
    ssum[t] = s; __syncthreads();
    for (int off = 1; off < 256; off <<= 1) {
        int x = (t >= off) ? ssum[t - off] : 0;
        __syncthreads();
        ssum[t] += x;
        __syncthreads();
    }
    int pre = ssum[t] - s;
    if (2 * t < cnt) {
        int node = lo + 2 * t;
        deg[node] = v0;
        offs[node] = s0 + pre;
        norm[node] = rsqrtf(fmaxf((float)v0, 1.0f));
    }
    if (2 * t + 1 < cnt) {
        int node = lo + 2 * t + 1;
        deg[node] = v1;
        offs[node] = s0 + pre + v0;
        norm[node] = rsqrtf(fmaxf((float)v1, 1.0f));
    }
    __syncthreads();
    h[2 * t] = pre;
    h[2 * t + 1] = pre + v0;
    __syncthreads();

    int wsize = s1 - s0;
    bool fits = (wsize <= CAP);
    for (int i = s0 + t; i < s1; i += 256) {
        int p = pairs[i];
        int dl = p >> 17;
        int sv = p & 0x1FFFF;
        int pos = atomicAdd(&h[dl], 1);
        if (fits) sbuf[pos] = sv; else esrc[s0 + pos] = sv;
    }
    __syncthreads();
    if (fits)
        for (int i = t; i < wsize; i += 256) esrc[s0 + i] = sbuf[i];
}

// ================= fused gather + GEMM (round 18, proven 80.5us) =================
__global__ __launch_bounds__(256) void k_gather_gemm(const unsigned* __restrict__ ft,
                                                     const int* __restrict__ offs,
                                                     const int* __restrict__ deg,
                                                     const int* __restrict__ esrc,
                                                     const float* __restrict__ norm,
                                                     const ushort* __restrict__ whi,
                                                     const ushort* __restrict__ wlo,
                                                     const float* __restrict__ bias,
                                                     float* __restrict__ out) {
    __shared__ ushort sA[16 * RPAD];
    const int wid  = threadIdx.x >> 6;
    const int lane = threadIdx.x & 63;
    const int g  = lane >> 4;
    const int sl = lane & 15;
    const int row0 = blockIdx.x * 16;
    const uint4v* ftv = (const uint4v*)ft;

    #pragma unroll
    for (int n4 = 0; n4 < 4; ++n4) {
        int n = wid * 4 + n4;
        int node = row0 + n;
        int start = offs[node];
        int cnt   = deg[node];
        int last  = start + cnt - 1;
        float acc[8] = {0.f, 0.f, 0.f, 0.f, 0.f, 0.f, 0.f, 0.f};
        for (int j = 0; j < cnt; j += 16) {
            int i0 = start + j + g;
            int s0v = esrc[min(i0,      last)];
            int s1v = esrc[min(i0 + 4,  last)];
            int s2v = esrc[min(i0 + 8,  last)];
            int s3v = esrc[min(i0 + 12, last)];
            float w0 = (j + g      < cnt) ? norm[s0v] : 0.0f;
            float w1 = (j + g + 4  < cnt) ? norm[s1v] : 0.0f;
            float w2 = (j + g + 8  < cnt) ? norm[s2v] : 0.0f;
            float w3 = (j + g + 12 < cnt) ? norm[s3v] : 0.0f;
            uint4v u0 = ftv[(size_t)s0v * 16 + sl];
            uint4v u1 = ftv[(size_t)s1v * 16 + sl];
            uint4v u2 = ftv[(size_t)s2v * 16 + sl];
            uint4v u3 = ftv[(size_t)s3v * 16 + sl];
            #pragma unroll
            for (int q = 0; q < 4; ++q) {
                unsigned a = u0[q];
                acc[q * 2]     = fmaf(__uint_as_float(a << 16),         w0, acc[q * 2]);
                acc[q * 2 + 1] = fmaf(__uint_as_float(a & 0xffff0000u), w0, acc[q * 2 + 1]);
            }
            #pragma unroll
            for (int q = 0; q < 4; ++q) {
                unsigned a = u1[q];
                acc[q * 2]     = fmaf(__uint_as_float(a << 16),         w1, acc[q * 2]);
                acc[q * 2 + 1] = fmaf(__uint_as_float(a & 0xffff0000u), w1, acc[q * 2 + 1]);
            }
            #pragma unroll
            for (int q = 0; q < 4; ++q) {
                unsigned a = u2[q];
                acc[q * 2]     = fmaf(__uint_as_float(a << 16),         w2, acc[q * 2]);
                acc[q * 2 + 1] = fmaf(__uint_as_float(a & 0xffff0000u), w2, acc[q * 2 + 1]);
            }
            #pragma unroll
            for (int q = 0; q < 4; ++q) {
                unsigned a = u3[q];
                acc[q * 2]     = fmaf(__uint_as_float(a << 16),         w3, acc[q * 2]);
                acc[q * 2 + 1] = fmaf(__uint_as_float(a & 0xffff0000u), w3, acc[q * 2 + 1]);
            }
        }
        #pragma unroll
        for (int q = 0; q < 8; ++q) {
            acc[q] += __shfl_xor(acc[q], 16, 64);
            acc[q] += __shfl_xor(acc[q], 32, 64);
        }
        if (g == 0) {
            uint4v o;
            #pragma unroll
            for (int q = 0; q < 4; ++q)
                o[q] = (unsigned)f2bf(acc[q * 2]) | ((unsigned)f2bf(acc[q * 2 + 1]) << 16);
            *(uint4v*)(&sA[n * RPAD + sl * 8]) = o;
        }
    }
    __syncthreads();

    const int rsub = lane & 15;
    const int kgrp = lane >> 4;
    short8 a[4];
    #pragma unroll
    for (int kt = 0; kt < 4; ++kt)
        a[kt] = *(const short8*)(&sA[rsub * RPAD + kt * 32 + kgrp * 8]);
    float nr[4];
    #pragma unroll
    for (int r = 0; r < 4; ++r) nr[r] = norm[row0 + kgrp * 4 + r];

    const short8* BH = (const short8*)whi;
    const short8* BL = (const short8*)wlo;
    #pragma unroll
    for (int cc = 0; cc < 2; ++cc) {
        int ct = wid * 2 + cc;
        f32x4 acc = {0.f, 0.f, 0.f, 0.f};
        #pragma unroll
        for (int kt = 0; kt < 4; ++kt) {
            acc = __builtin_amdgcn_mfma_f32_16x16x32_bf16(a[kt], BH[(ct * 4 + kt) * 64 + lane], acc, 0, 0, 0);
            acc = __builtin_amdgcn_mfma_f32_16x16x32_bf16(a[kt], BL[(ct * 4 + kt) * 64 + lane], acc, 0, 0, 0);
        }
        const float bc = bias[ct * 16 + rsub];
        float* ocol = out + (size_t)row0 * D + ct * 16 + rsub;
        #pragma unroll
        for (int r = 0; r < 4; ++r) {
            int row = kgrp * 4 + r;
            ocol[(size_t)row * D] = acc[r] * nr[r] + bc;
        }
    }
}

// ---------------- last-resort fallback (atomic scatter) ----------------
__global__ void k_scatter(const float* __restrict__ feat, const int* __restrict__ src,
                          const int* __restrict__ dst, const float* __restrict__ norm,
                          int E, float* __restrict__ agg) {
    long long gtid = (long long)blockIdx.x * blockDim.x + threadIdx.x;
    int e    = (int)(gtid >> 6);
    int lane = (int)(gtid & 63);
    if (e >= E) return;
    int s = src[e];
    int t = dst[e];
    float ns = norm[s];
    float2 v = ((const float2*)(feat + (size_t)s * D))[lane];
    float* arow = agg + (size_t)t * D + lane * 2;
    atomicAdd(arow + 0, v.x * ns);
    atomicAdd(arow + 1, v.y * ns);
}
__global__ void k_deg_f(const int* __restrict__ dst, int E, float* __restrict__ deg) {
    int i = blockIdx.x * blockDim.x + threadIdx.x;
    if (i < E) atomicAdd(deg + dst[i], 1.0f);
}
__global__ void k_norm_f(float* __restrict__ dn) {
    int i = blockIdx.x * blockDim.x + threadIdx.x;
    if (i < N_NODES) dn[i] = rsqrtf(fmaxf(dn[i], 1.0f));
}
__global__ __launch_bounds__(256) void k_gemm(float* __restrict__ io,
                                              const float* __restrict__ W,
                                              const float* __restrict__ bias,
                                              const float* __restrict__ norm) {
    __shared__ float sW[D * D];
    __shared__ float srow[2][D];
    for (int i = threadIdx.x; i < D * D; i += 256) sW[i] = W[i];
    const int r = threadIdx.x >> 7;
    const int c = threadIdx.x & 127;
    const float bc = bias[c];
    const int npairs = N_NODES / 2;
    for (int rp = blockIdx.x; rp < npairs; rp += gridDim.x) {
        __syncthreads();
        const int row = rp * 2 + r;
        srow[r][c] = io[(size_t)row * D + c];
        __syncthreads();
        float acc = 0.f;
        #pragma unroll 8
        for (int k = 0; k < D; ++k)
            acc = fmaf(srow[r][k], sW[k * D + c], acc);
        io[(size_t)row * D + c] = acc * norm[row] + bc;
    }
}

extern "C" void kernel_launch(void* const* d_in, const int* in_sizes, int n_in,
                              void* d_out, int out_size, void* d_ws, size_t ws_size,
                              hipStream_t stream) {
    const float* feat   = (const float*)d_in[0];
    const float* weight = (const float*)d_in[1];
    const float* bias   = (const float*)d_in[2];
    const int*   src    = (const int*)d_in[3];
    const int*   dst    = (const int*)d_in[4];
    int E = in_sizes[3];

    int* pairs = (int*)d_out;    // d_out doubles as pairs scratch (dead before output written)

    // ---- workspace allocator (64B aligned) ----
    uintptr_t cur = (uintptr_t)d_ws;
    auto take = [&](size_t bytes) -> void* {
        uintptr_t r = (cur + 63) & ~(uintptr_t)63;
        cur = r + bytes;
        return (void*)r;
    };

    size_t S_ft  = (size_t)N_NODES * 64 * 4;     // 25.6 MB
    size_t need  = S_ft +
                   (size_t)(3 * N_NODES + 256 + NB * NB + E) * 4 + 65536 + 1024;

    unsigned* ft     = (unsigned*)take(S_ft);
    float*    norm   = (float*)take((size_t)N_NODES * 4);
    int*      deg    = (int*)take((size_t)N_NODES * 4);
    int*      offs   = (int*)take((size_t)N_NODES * 4);
    int*      rowtot = (int*)take(256 * 4);
    int*      bhist  = (int*)take((size_t)NB * NB * 4);
    int*      esrc   = (int*)take((size_t)E * 4);
    ushort*   whi    = (ushort*)take(16384 * 2);
    ushort*   wlo    = (ushort*)take(16384 * 2);

    if (ws_size >= need) {
        uint2* ft2 = (uint2*)ft;
        void* args[] = {(void*)&src, (void*)&dst, (void*)&E, (void*)&weight,
                        (void*)&whi, (void*)&wlo, (void*)&feat, (void*)&ft2,
                        (void*)&bhist, (void*)&rowtot, (void*)&pairs,
                        (void*)&deg, (void*)&offs, (void*)&norm, (void*)&esrc};
        hipError_t err = hipLaunchCooperativeKernel((const void*)k_sort_coop,
                                                    dim3(NB), dim3(256), args, 0, stream);
        if (err != hipSuccess) {
            // fallback: separate sort dispatches (round-18 path, proven)
            p1_histo_conv<<<NB + CONVB, 256, 0, stream>>>(dst, E, bhist, weight, whi, wlo,
                                                          feat, (uint2*)ft);
            p1_scanrow<<<NB, 256, 0, stream>>>(bhist, rowtot);
            p1_scatter<<<NB, 256, 0, stream>>>(src, dst, E, bhist, rowtot, pairs);
            p2_all<<<NB, 256, 0, stream>>>(pairs, rowtot, deg, offs, norm, esrc);
        }
        k_gather_gemm<<<N_NODES / 16, 256, 0, stream>>>(ft, offs, deg, esrc, norm,
                                                        whi, wlo, bias, (float*)d_out);
    } else {
        // last-resort: atomic scatter path (fp32 end-to-end)
        float* agg = (float*)d_out;
        hipMemsetAsync(d_out, 0, (size_t)N_NODES * D * sizeof(float), stream);
        hipMemsetAsync(norm, 0, (size_t)N_NODES * sizeof(float), stream);
        k_deg_f<<<(E + 255) / 256, 256, 0, stream>>>(dst, E, (float*)norm);
        k_norm_f<<<(N_NODES + 255) / 256, 256, 0, stream>>>((float*)norm);
        long long sthreads = (long long)E * 64;
        k_scatter<<<(int)((sthreads + 255) / 256), 256, 0, stream>>>(feat, src, dst, (float*)norm, E, agg);
        k_gemm<<<4096, 256, 0, stream>>>(agg, weight, bias, (float*)norm);
    }
}

// Round 20
// 133.625 us; speedup vs baseline: 1.7723x; 1.7723x over previous
//
#include <hip/hip_runtime.h>

// GraphConv: counting-sort CSR + FUSED bf16 gather + per-block MFMA GEMM.
// Round 20: REVERT round-19 cooperative sort (1 block/CU starved the conversion:
//           11% occupancy, 150us). Round-18 configuration restored verbatim —
//           proven best at 133.7us:
//   - p1_histo_conv (histogram + W-pack + 1280 concurrent conversion blocks)
//   - p1_scanrow / p1_scatter / p2_all  (parallel LDS scans, LDS-staged scatter)
//   - k_gather_gemm: 6250 blocks x 4 waves; wave gathers 4 nodes (16 edges/iter,
//     MLP-4), shared 16-row LDS tile, MFMA split across waves (B from L2 whi/wlo).

constexpr int N_NODES = 100000;
constexpr int D = 128;
constexpr int NB = 256;                        // coarse buckets
constexpr int GROUP = (N_NODES + NB - 1) / NB; // 391 nodes per bucket
constexpr int CAP = 14336;                     // LDS esrc staging capacity (56KB)
constexpr int CONVB = 1280;                    // extra conversion blocks in p1 dispatch
constexpr int RPAD = 136;                      // LDS A-tile row stride in ushorts (272B)

typedef float f32x4 __attribute__((ext_vector_type(4)));
typedef short short8 __attribute__((ext_vector_type(8)));
typedef unsigned uint4v __attribute__((ext_vector_type(4)));

__device__ __forceinline__ ushort f2bf(float x) {            // fp32 -> bf16 RNE
    unsigned u = __float_as_uint(x);
    return (ushort)((u + 0x7fffu + ((u >> 16) & 1u)) >> 16);
}
__device__ __forceinline__ float bf2f(ushort h) {
    return __uint_as_float(((unsigned)h) << 16);
}

// ---------------- pass 1: coarse histogram + W pack + feat->bf16 conversion ----------------
__global__ __launch_bounds__(256) void p1_histo_conv(const int* __restrict__ dst, int E,
                                                     int* __restrict__ bhist,      // [bucket][chunk]
                                                     const float* __restrict__ W,
                                                     ushort* __restrict__ whi,
                                                     ushort* __restrict__ wlo,
                                                     const float* __restrict__ feat,
                                                     uint2* __restrict__ ft2) {
    int t = threadIdx.x, blk = blockIdx.x;
    if (blk >= NB) {                      // conversion blocks: ft = bf16(feat), no norm
        int base = (blk - NB) * 256 + t;
        int stride = CONVB * 256;
        for (int i = base; i < N_NODES * 32; i += stride) {
            f32x4 v = ((const f32x4*)feat)[i];
            uint2 o;
            o.x = (unsigned)f2bf(v[0]) | ((unsigned)f2bf(v[1]) << 16);
            o.y = (unsigned)f2bf(v[2]) | ((unsigned)f2bf(v[3]) << 16);
            ft2[i] = o;
        }
        return;
    }
    __shared__ int h[NB];
    h[t] = 0;
    if (blk < 64) {                       // fold k_wpack: 64*256 = 16384 elements
        int p = blk * 256 + t;
        int i  = p & 7;
        int l  = (p >> 3) & 63;
        int kt = (p >> 9) & 3;
        int ct = (p >> 11);
        int k = kt * 32 + (l >> 4) * 8 + i;
        int n = ct * 16 + (l & 15);
        float x = W[k * 128 + n];
        ushort hh = f2bf(x);
        whi[p] = hh;
        wlo[p] = f2bf(x - bf2f(hh));
    }
    __syncthreads();
    int per = (E + NB - 1) / NB;
    int s = blk * per, e = min(E, s + per);
    for (int i = s + t; i < e; i += 256) atomicAdd(&h[dst[i] / GROUP], 1);
    __syncthreads();
    bhist[t * NB + blk] = h[t];          // bucket-major [bucket][chunk]
}

// 256 blocks: block b exclusive-scans bucket row b over chunks; writes rowtot[b].
__global__ __launch_bounds__(256) void p1_scanrow(int* __restrict__ bhist,
                                                  int* __restrict__ rowtot) {
    __shared__ int lds[256];
    int b = blockIdx.x, t = threadIdx.x;
    int v = bhist[b * NB + t];
    lds[t] = v; __syncthreads();
    for (int off = 1; off < 256; off <<= 1) {
        int x = (t >= off) ? lds[t - off] : 0;
        __syncthreads();
        lds[t] += x;
        __syncthreads();
    }
    bhist[b * NB + t] = lds[t] - v;      // exclusive within bucket row
    if (t == 255) rowtot[b] = lds[255];
}

// Scatter packed (dloc<<17 | src) into coarse-bucket regions; bktBase recomputed in LDS.
__global__ __launch_bounds__(256) void p1_scatter(const int* __restrict__ src,
                                                  const int* __restrict__ dst, int E,
                                                  const int* __restrict__ bhist,
                                                  const int* __restrict__ rowtot,
                                                  int* __restrict__ pairs) {
    __shared__ int loff[NB];
    __shared__ int bb[NB];
    int t = threadIdx.x, blk = blockIdx.x;
    int rv = rowtot[t];
    bb[t] = rv; __syncthreads();
    for (int off = 1; off < 256; off <<= 1) {
        int x = (t >= off) ? bb[t - off] : 0;
        __syncthreads();
        bb[t] += x;
        __syncthreads();
    }
    loff[t] = bhist[t * NB + blk] + bb[t] - rv;   // chunk offset + bucket base
    __syncthreads();
    int per = (E + NB - 1) / NB;
    int s = blk * per, e = min(E, s + per);
    for (int i = s + t; i < e; i += 256) {
        int d = dst[i];
        int b = d / GROUP;
        int pos = atomicAdd(&loff[b], 1);
        pairs[pos] = ((d - b * GROUP) << 17) | src[i];
    }
}

// ---------------- pass 2 (fused): fine histogram -> deg/offs/norm, then esrc scatter ----------------
__global__ __launch_bounds__(256) void p2_all(const int* __restrict__ pairs,
                                              const int* __restrict__ rowtot,
                                              int* __restrict__ deg,
                                              int* __restrict__ offs,
                                              float* __restrict__ norm,
                                              int* __restrict__ esrc) {
    __shared__ int h[512];            // fine histogram, then in-bucket position counters
    __shared__ int ssum[256];
    __shared__ int bb[256];
    __shared__ int sbuf[CAP];
    int t = threadIdx.x, b = blockIdx.x;
    int lo = b * GROUP;
    int cnt = min(GROUP, N_NODES - lo);

    int rv = rowtot[t];
    bb[t] = rv;
    h[t] = 0; h[t + 256] = 0;
    __syncthreads();
    for (int off = 1; off < 256; off <<= 1) {
        int x = (t >= off) ? bb[t - off] : 0;
        __syncthreads();
        bb[t] += x;
        __syncthreads();
    }
    int s1 = bb[b];
    int s0 = s1 - rowtot[b];
    __syncthreads();

    for (int i = s0 + t; i < s1; i += 256) atomicAdd(&h[pairs[i] >> 17], 1);
    __syncthreads();

    int v0 = h[2 * t], v1 = h[2 * t + 1];
    int s = v0 + v1;
    ssum[t] = s; __syncthreads();
    for (int off = 1; off < 256; off <<= 1) {
        int x = (t >= off) ? ssum[t - off] : 0;
        __syncthreads();
        ssum[t] += x;
        __syncthreads();
    }
    int pre = ssum[t] - s;            // exclusive prefix of node 2t within bucket
    if (2 * t < cnt) {
        int node = lo + 2 * t;
        deg[node] = v0;
        offs[node] = s0 + pre;
        norm[node] = rsqrtf(fmaxf((float)v0, 1.0f));
    }
    if (2 * t + 1 < cnt) {
        int node = lo + 2 * t + 1;
        deg[node] = v1;
        offs[node] = s0 + pre + v0;
        norm[node] = rsqrtf(fmaxf((float)v1, 1.0f));
    }
    __syncthreads();
    h[2 * t] = pre;
    h[2 * t + 1] = pre + v0;
    __syncthreads();

    int wsize = s1 - s0;
    bool fits = (wsize <= CAP);
    for (int i = s0 + t; i < s1; i += 256) {
        int p = pairs[i];
        int dl = p >> 17;
        int sv = p & 0x1FFFF;
        int pos = atomicAdd(&h[dl], 1);
        if (fits) sbuf[pos] = sv; else esrc[s0 + pos] = sv;
    }
    __syncthreads();
    if (fits)
        for (int i = t; i < wsize; i += 256) esrc[s0 + i] = sbuf[i];
}

// ---------------- fused gather + GEMM: 6250 blocks, wave gathers 4 nodes ----------------
__global__ __launch_bounds__(256) void k_gather_gemm(const unsigned* __restrict__ ft,
                                                     const int* __restrict__ offs,
                                                     const int* __restrict__ deg,
                                                     const int* __restrict__ esrc,
                                                     const float* __restrict__ norm,
                                                     const ushort* __restrict__ whi,
                                                     const ushort* __restrict__ wlo,
                                                     const float* __restrict__ bias,
                                                     float* __restrict__ out) {
    __shared__ ushort sA[16 * RPAD];          // shared 16x128 bf16 A-tile, padded rows
    const int wid  = threadIdx.x >> 6;
    const int lane = threadIdx.x & 63;
    const int g  = lane >> 4;                 // edge subgroup 0..3
    const int sl = lane & 15;                 // 16 lanes x uint4 = 256B row
    const int row0 = blockIdx.x * 16;
    const uint4v* ftv = (const uint4v*)ft;

    #pragma unroll
    for (int n4 = 0; n4 < 4; ++n4) {          // wave gathers nodes row0 + wid*4 + n4
        int n = wid * 4 + n4;
        int node = row0 + n;
        int start = offs[node];
        int cnt   = deg[node];
        int last  = start + cnt - 1;
        float acc[8] = {0.f, 0.f, 0.f, 0.f, 0.f, 0.f, 0.f, 0.f};
        for (int j = 0; j < cnt; j += 16) {
            int i0 = start + j + g;
            int s0v = esrc[min(i0,      last)];
            int s1v = esrc[min(i0 + 4,  last)];
            int s2v = esrc[min(i0 + 8,  last)];
            int s3v = esrc[min(i0 + 12, last)];
            float w0 = (j + g      < cnt) ? norm[s0v] : 0.0f;
            float w1 = (j + g + 4  < cnt) ? norm[s1v] : 0.0f;
            float w2 = (j + g + 8  < cnt) ? norm[s2v] : 0.0f;
            float w3 = (j + g + 12 < cnt) ? norm[s3v] : 0.0f;
            uint4v u0 = ftv[(size_t)s0v * 16 + sl];        // 4 independent 16B loads
            uint4v u1 = ftv[(size_t)s1v * 16 + sl];
            uint4v u2 = ftv[(size_t)s2v * 16 + sl];
            uint4v u3 = ftv[(size_t)s3v * 16 + sl];
            #pragma unroll
            for (int q = 0; q < 4; ++q) {
                unsigned a = u0[q];
                acc[q * 2]     = fmaf(__uint_as_float(a << 16),         w0, acc[q * 2]);
                acc[q * 2 + 1] = fmaf(__uint_as_float(a & 0xffff0000u), w0, acc[q * 2 + 1]);
            }
            #pragma unroll
            for (int q = 0; q < 4; ++q) {
                unsigned a = u1[q];
                acc[q * 2]     = fmaf(__uint_as_float(a << 16),         w1, acc[q * 2]);
                acc[q * 2 + 1] = fmaf(__uint_as_float(a & 0xffff0000u), w1, acc[q * 2 + 1]);
            }
            #pragma unroll
            for (int q = 0; q < 4; ++q) {
                unsigned a = u2[q];
                acc[q * 2]     = fmaf(__uint_as_float(a << 16),         w2, acc[q * 2]);
                acc[q * 2 + 1] = fmaf(__uint_as_float(a & 0xffff0000u), w2, acc[q * 2 + 1]);
            }
            #pragma unroll
            for (int q = 0; q < 4; ++q) {
                unsigned a = u3[q];
                acc[q * 2]     = fmaf(__uint_as_float(a << 16),         w3, acc[q * 2]);
                acc[q * 2 + 1] = fmaf(__uint_as_float(a & 0xffff0000u), w3, acc[q * 2 + 1]);
            }
        }
        #pragma unroll
        for (int q = 0; q < 8; ++q) {
            acc[q] += __shfl_xor(acc[q], 16, 64);
            acc[q] += __shfl_xor(acc[q], 32, 64);
        }
        if (g == 0) {                          // 16 lanes store the bf16 row (16B each)
            uint4v o;
            #pragma unroll
            for (int q = 0; q < 4; ++q)
                o[q] = (unsigned)f2bf(acc[q * 2]) | ((unsigned)f2bf(acc[q * 2 + 1]) << 16);
            *(uint4v*)(&sA[n * RPAD + sl * 8]) = o;
        }
    }
    __syncthreads();

    // MFMA: wave handles ct = wid*2 + {0,1}
    const int rsub = lane & 15;
    const int kgrp = lane >> 4;
    short8 a[4];
    #pragma unroll
    for (int kt = 0; kt < 4; ++kt)
        a[kt] = *(const short8*)(&sA[rsub * RPAD + kt * 32 + kgrp * 8]);
    float nr[4];
    #pragma unroll
    for (int r = 0; r < 4; ++r) nr[r] = norm[row0 + kgrp * 4 + r];

    const short8* BH = (const short8*)whi;     // L2-resident fragment-ordered W
    const short8* BL = (const short8*)wlo;
    #pragma unroll
    for (int cc = 0; cc < 2; ++cc) {
        int ct = wid * 2 + cc;
        f32x4 acc = {0.f, 0.f, 0.f, 0.f};
        #pragma unroll
        for (int kt = 0; kt < 4; ++kt) {
            acc = __builtin_amdgcn_mfma_f32_16x16x32_bf16(a[kt], BH[(ct * 4 + kt) * 64 + lane], acc, 0, 0, 0);
            acc = __builtin_amdgcn_mfma_f32_16x16x32_bf16(a[kt], BL[(ct * 4 + kt) * 64 + lane], acc, 0, 0, 0);
        }
        // C/D: col = ct*16 + rsub, row = kgrp*4 + r  [m89 verified mapping]
        const float bc = bias[ct * 16 + rsub];
        float* ocol = out + (size_t)row0 * D + ct * 16 + rsub;
        #pragma unroll
        for (int r = 0; r < 4; ++r) {
            int row = kgrp * 4 + r;
            ocol[(size_t)row * D] = acc[r] * nr[r] + bc;
        }
    }
}

// ---------------- last-resort fallback (atomic scatter) ----------------
__global__ void k_scatter(const float* __restrict__ feat, const int* __restrict__ src,
                          const int* __restrict__ dst, const float* __restrict__ norm,
                          int E, float* __restrict__ agg) {
    long long gtid = (long long)blockIdx.x * blockDim.x + threadIdx.x;
    int e    = (int)(gtid >> 6);
    int lane = (int)(gtid & 63);
    if (e >= E) return;
    int s = src[e];
    int t = dst[e];
    float ns = norm[s];
    float2 v = ((const float2*)(feat + (size_t)s * D))[lane];
    float* arow = agg + (size_t)t * D + lane * 2;
    atomicAdd(arow + 0, v.x * ns);
    atomicAdd(arow + 1, v.y * ns);
}
__global__ void k_deg_f(const int* __restrict__ dst, int E, float* __restrict__ deg) {
    int i = blockIdx.x * blockDim.x + threadIdx.x;
    if (i < E) atomicAdd(deg + dst[i], 1.0f);
}
__global__ void k_norm_f(float* __restrict__ dn) {
    int i = blockIdx.x * blockDim.x + threadIdx.x;
    if (i < N_NODES) dn[i] = rsqrtf(fmaxf(dn[i], 1.0f));
}
__global__ __launch_bounds__(256) void k_gemm(float* __restrict__ io,
                                              const float* __restrict__ W,
                                              const float* __restrict__ bias,
                                              const float* __restrict__ norm) {
    __shared__ float sW[D * D];
    __shared__ float srow[2][D];
    for (int i = threadIdx.x; i < D * D; i += 256) sW[i] = W[i];
    const int r = threadIdx.x >> 7;
    const int c = threadIdx.x & 127;
    const float bc = bias[c];
    const int npairs = N_NODES / 2;
    for (int rp = blockIdx.x; rp < npairs; rp += gridDim.x) {
        __syncthreads();
        const int row = rp * 2 + r;
        srow[r][c] = io[(size_t)row * D + c];
        __syncthreads();
        float acc = 0.f;
        #pragma unroll 8
        for (int k = 0; k < D; ++k)
            acc = fmaf(srow[r][k], sW[k * D + c], acc);
        io[(size_t)row * D + c] = acc * norm[row] + bc;
    }
}

extern "C" void kernel_launch(void* const* d_in, const int* in_sizes, int n_in,
                              void* d_out, int out_size, void* d_ws, size_t ws_size,
                              hipStream_t stream) {
    const float* feat   = (const float*)d_in[0];
    const float* weight = (const float*)d_in[1];
    const float* bias   = (const float*)d_in[2];
    const int*   src    = (const int*)d_in[3];
    const int*   dst    = (const int*)d_in[4];
    const int E = in_sizes[3];

    int* pairs = (int*)d_out;    // d_out doubles as pairs scratch (dead before output written)

    // ---- workspace allocator (64B aligned) ----
    uintptr_t cur = (uintptr_t)d_ws;
    auto take = [&](size_t bytes) -> void* {
        uintptr_t r = (cur + 63) & ~(uintptr_t)63;
        cur = r + bytes;
        return (void*)r;
    };

    size_t S_ft  = (size_t)N_NODES * 64 * 4;     // 25.6 MB
    size_t need  = S_ft +
                   (size_t)(3 * N_NODES + 256 + NB * NB + E) * 4 + 65536 + 1024;

    unsigned* ft     = (unsigned*)take(S_ft);
    float*    norm   = (float*)take((size_t)N_NODES * 4);
    int*      deg    = (int*)take((size_t)N_NODES * 4);
    int*      offs   = (int*)take((size_t)N_NODES * 4);
    int*      rowtot = (int*)take(256 * 4);
    int*      bhist  = (int*)take((size_t)NB * NB * 4);
    int*      esrc   = (int*)take((size_t)E * 4);
    ushort*   whi    = (ushort*)take(16384 * 2);
    ushort*   wlo    = (ushort*)take(16384 * 2);

    if (ws_size >= need) {
        p1_histo_conv<<<NB + CONVB, 256, 0, stream>>>(dst, E, bhist, weight, whi, wlo,
                                                      feat, (uint2*)ft);
        p1_scanrow<<<NB, 256, 0, stream>>>(bhist, rowtot);
        p1_scatter<<<NB, 256, 0, stream>>>(src, dst, E, bhist, rowtot, pairs);
        p2_all<<<NB, 256, 0, stream>>>(pairs, rowtot, deg, offs, norm, esrc);
        k_gather_gemm<<<N_NODES / 16, 256, 0, stream>>>(ft, offs, deg, esrc, norm,
                                                        whi, wlo, bias, (float*)d_out);
    } else {
        // last-resort: atomic scatter path (fp32 end-to-end)
        float* agg = (float*)d_out;
        hipMemsetAsync(d_out, 0, (size_t)N_NODES * D * sizeof(float), stream);
        hipMemsetAsync(norm, 0, (size_t)N_NODES * sizeof(float), stream);
        k_deg_f<<<(E + 255) / 256, 256, 0, stream>>>(dst, E, (float*)norm);
        k_norm_f<<<(N_NODES + 255) / 256, 256, 0, stream>>>((float*)norm);
        long long sthreads = (long long)E * 64;
        k_scatter<<<(int)((sthreads + 255) / 256), 256, 0, stream>>>(feat, src, dst, (float*)norm, E, agg);
        k_gemm<<<4096, 256, 0, stream>>>(agg, weight, bias, (float*)norm);
    }
}